// Round 2
// baseline (4536.663 us; speedup 1.0000x reference)
//
#include <hip/hip_runtime.h>
#include <hip/hip_bf16.h>
#include <stdint.h>
#include <stddef.h>

#define N_NODES 30000
#define N_EDGES 480000
#define EN_TOT  (N_EDGES + N_NODES)   /* 510000 with self loops */
#define F_IN 4096
#define HEADS 4
#define HID 128
#define D1 (HEADS * HID)              /* 512 */
#define CLS 6
#define NEG_SLOPE 0.2f

typedef __attribute__((ext_vector_type(4))) unsigned int u32x4;
typedef __attribute__((ext_vector_type(8))) short short8;
typedef __attribute__((ext_vector_type(4))) float f32x4;

// bf16 (stored as ushort) <-> f32 helpers, explicit bit manipulation
__device__ __forceinline__ float bf2f(unsigned short u) {
  return __uint_as_float(((unsigned int)u) << 16);
}
__device__ __forceinline__ unsigned short f2bf(float f) {
  unsigned int u = __float_as_uint(f);
  unsigned int r = (u + 0x7FFFu + ((u >> 16) & 1u)) >> 16;  // RNE
  return (unsigned short)r;
}
// dtype-flexible scalar input load. isbf: 1 = buffer holds bf16, 0 = f32.
__device__ __forceinline__ float ldin(const void* p, int isbf, size_t i) {
  if (isbf) return bf2f(((const unsigned short*)p)[i]);
  return ((const float*)p)[i];
}

// ---------------------------------------------------------------- dtype detect
// f32 data misread as bf16 -> garbage mantissa words (many inf/NaN/huge).
// bf16 data read as bf16 -> all sane. One-sided test on bf16 interpretation.
__global__ void k_detect(const void* xraw, int* flag) {
  __shared__ int bad;
  if (threadIdx.x == 0) bad = 0;
  __syncthreads();
  const unsigned short* u = (const unsigned short*)xraw;
  int cnt = 0;
  for (int i = threadIdx.x; i < 8192; i += 256) {
    float v = bf2f(u[i]);
    if (!isfinite(v) || fabsf(v) > 1e8f) cnt++;
  }
  atomicAdd(&bad, cnt);
  __syncthreads();
  if (threadIdx.x == 0) *flag = (bad > 8) ? 0 : 1;  // 1 = bf16 mode
}

// ---------------------------------------------------------------- zero fill
__global__ void k_zero(float* __restrict__ p, long long n) {
  long long i = (long long)blockIdx.x * blockDim.x + threadIdx.x;
  if (i < n) p[i] = 0.f;
}

// ---------------------------------------------------------------- W1 transpose: [F_IN, D1] -> bf16 [D1, F_IN]
__global__ void k_transpose(const void* __restrict__ in, unsigned short* __restrict__ out,
                            const int* __restrict__ flag) {
  const int isbf = *flag;
  __shared__ unsigned short t[32][33];
  int bx = blockIdx.x * 32;  // col (n) base
  int by = blockIdx.y * 32;  // row (k) base
  int x = threadIdx.x, y = threadIdx.y;  // 32 x 8
#pragma unroll
  for (int i = 0; i < 32; i += 8)
    t[y + i][x] = f2bf(ldin(in, isbf, (size_t)(by + y + i) * D1 + bx + x));
  __syncthreads();
#pragma unroll
  for (int i = 0; i < 32; i += 8)
    out[(size_t)(bx + y + i) * F_IN + by + x] = t[x][y + i];
}

// ---------------------------------------------------------------- GEMM1: h1[30000,512] = x @ W1 (bf16 MFMA)
__launch_bounds__(256, 2)
__global__ void k_gemm1(const void* __restrict__ xraw, const unsigned short* __restrict__ w1t,
                        unsigned short* __restrict__ h1, const int* __restrict__ flag) {
  const int isbf = *flag;
  __shared__ __align__(16) unsigned short As[128 * 32];
  __shared__ __align__(16) unsigned short Bs[128 * 32];
  const int tid = threadIdx.x;
  const int wave = tid >> 6, lane = tid & 63;
  const int l15 = lane & 15, lq = lane >> 4;
  const int wm = (wave & 1) * 64, wn = (wave >> 1) * 64;
  const int n0 = blockIdx.x * 128;   // N tile (4)
  const int m0 = blockIdx.y * 128;   // M tile (235)

  f32x4 acc[4][4];
#pragma unroll
  for (int i = 0; i < 4; i++)
#pragma unroll
    for (int j = 0; j < 4; j++) acc[i][j] = (f32x4){0.f, 0.f, 0.f, 0.f};

  const u32x4* As4 = (const u32x4*)As;
  const u32x4* Bs4 = (const u32x4*)Bs;

  for (int k0 = 0; k0 < F_IN; k0 += 32) {
#pragma unroll
    for (int it = 0; it < 2; ++it) {
      int idx = it * 256 + tid;       // 0..511 chunks of 8 bf16 (16B)
      int row = idx >> 2;             // 0..127
      int c8  = (idx & 3) * 8;        // 0,8,16,24
      int gr  = m0 + row;
      u32x4 av = {0u, 0u, 0u, 0u};
      if (gr < N_NODES) {
        size_t eoff = (size_t)gr * F_IN + k0 + c8;
        if (isbf) {
          av = *(const u32x4*)((const unsigned short*)xraw + eoff);
        } else {
          const float* xf = (const float*)xraw + eoff;
          float4 v0 = *(const float4*)xf;
          float4 v1 = *(const float4*)(xf + 4);
          av[0] = (unsigned int)f2bf(v0.x) | ((unsigned int)f2bf(v0.y) << 16);
          av[1] = (unsigned int)f2bf(v0.z) | ((unsigned int)f2bf(v0.w) << 16);
          av[2] = (unsigned int)f2bf(v1.x) | ((unsigned int)f2bf(v1.y) << 16);
          av[3] = (unsigned int)f2bf(v1.z) | ((unsigned int)f2bf(v1.w) << 16);
        }
      }
      u32x4 bv = *(const u32x4*)(w1t + (size_t)(n0 + row) * F_IN + k0 + c8);
      ((u32x4*)As)[idx] = av;
      ((u32x4*)Bs)[idx] = bv;
    }
    __syncthreads();
    short8 af[4], bfr[4];
#pragma unroll
    for (int i = 0; i < 4; i++)
      af[i] = __builtin_bit_cast(short8, As4[(wm + 16 * i + l15) * 4 + lq]);
#pragma unroll
    for (int j = 0; j < 4; j++)
      bfr[j] = __builtin_bit_cast(short8, Bs4[(wn + 16 * j + l15) * 4 + lq]);
#pragma unroll
    for (int i = 0; i < 4; i++)
#pragma unroll
      for (int j = 0; j < 4; j++)
        acc[i][j] = __builtin_amdgcn_mfma_f32_16x16x32_bf16(af[i], bfr[j], acc[i][j], 0, 0, 0);
    __syncthreads();
  }
  // C/D layout: col=lane&15, row=(lane>>4)*4+reg  [m89-verified]
#pragma unroll
  for (int i = 0; i < 4; i++) {
#pragma unroll
    for (int r = 0; r < 4; r++) {
      int row = m0 + wm + 16 * i + lq * 4 + r;
      if (row < N_NODES) {
#pragma unroll
        for (int j = 0; j < 4; j++) {
          int col = n0 + wn + 16 * j + l15;
          h1[(size_t)row * D1 + col] = f2bf(acc[i][j][r]);
        }
      }
    }
  }
}

// ---------------------------------------------------------------- per-node attention coefficients, layer 1
__global__ void k_alpha1(const unsigned short* __restrict__ h1, const void* __restrict__ a_s,
                         const void* __restrict__ a_d, float* __restrict__ as1,
                         float* __restrict__ ad1, const int* __restrict__ flag) {
  const int isbf = *flag;
  int n = blockIdx.x;
  int h = threadIdx.x >> 6;
  int lane = threadIdx.x & 63;
  const unsigned short* hp = h1 + (size_t)n * D1 + h * HID;
  float s0 = 0.f, s1 = 0.f;
#pragma unroll
  for (int t = 0; t < 2; ++t) {
    int c = lane + t * 64;
    float hv = bf2f(hp[c]);
    s0 += hv * ldin(a_s, isbf, h * HID + c);
    s1 += hv * ldin(a_d, isbf, h * HID + c);
  }
#pragma unroll
  for (int off = 32; off > 0; off >>= 1) {
    s0 += __shfl_down(s0, off, 64);
    s1 += __shfl_down(s1, off, 64);
  }
  if (lane == 0) { as1[n * HEADS + h] = s0; ad1[n * HEADS + h] = s1; }
}

// ---------------------------------------------------------------- edge logits + denom, layer 1
// softmax without max-shift: shift-invariant and |e| <~ 12 here, exp() safe
__global__ void k_edge1(const int* __restrict__ ei, const float* __restrict__ as1,
                        const float* __restrict__ ad1, float* __restrict__ p1,
                        float* __restrict__ denom1) {
  int i = blockIdx.x * blockDim.x + threadIdx.x;
  if (i >= EN_TOT) return;
  int s, d;
  if (i < N_EDGES) { s = ei[i]; d = ei[N_EDGES + i]; }
  else { s = d = i - N_EDGES; }
#pragma unroll
  for (int h = 0; h < HEADS; ++h) {
    float e = as1[s * HEADS + h] + ad1[d * HEADS + h];
    e = e > 0.f ? e : NEG_SLOPE * e;
    float p = __expf(e);
    p1[i * HEADS + h] = p;
    atomicAdd(&denom1[d * HEADS + h], p);
  }
}

__global__ void k_norm1(const int* __restrict__ ei, float* __restrict__ p1,
                        const float* __restrict__ denom1) {
  int i = blockIdx.x * blockDim.x + threadIdx.x;
  if (i >= EN_TOT) return;
  int d = (i < N_EDGES) ? ei[N_EDGES + i] : i - N_EDGES;
#pragma unroll
  for (int h = 0; h < HEADS; ++h)
    p1[i * HEADS + h] = p1[i * HEADS + h] / denom1[d * HEADS + h];
}

// ---------------------------------------------------------------- aggregation layer 1: out1[d] += alpha * h1[s]
// one thread = one (edge, 4-channel group)
__global__ void k_agg1(const int* __restrict__ ei, const float* __restrict__ p1,
                       const unsigned short* __restrict__ h1, float* __restrict__ out1) {
  const long long total = (long long)EN_TOT * (D1 / 4);
  long long gid = (long long)blockIdx.x * blockDim.x + threadIdx.x;
  const long long stride = (long long)gridDim.x * blockDim.x;
  for (; gid < total; gid += stride) {
    int i  = (int)(gid >> 7);        // edge id
    int c4 = (int)(gid & 127);       // 4-channel group
    int c  = c4 * 4;
    int h  = c >> 7;
    int s, d;
    if (i < N_EDGES) { s = ei[i]; d = ei[N_EDGES + i]; }
    else { s = d = i - N_EDGES; }
    float alpha = p1[i * HEADS + h];
    const unsigned short* hp = h1 + (size_t)s * D1 + c;
    ushort4 hv = *(const ushort4*)hp;
    float* op = out1 + (size_t)d * D1 + c;
    atomicAdd(op + 0, alpha * bf2f(hv.x));
    atomicAdd(op + 1, alpha * bf2f(hv.y));
    atomicAdd(op + 2, alpha * bf2f(hv.z));
    atomicAdd(op + 3, alpha * bf2f(hv.w));
  }
}

// ---------------------------------------------------------------- layer 2 fused: x2 = elu(out1 + b1); h2 = x2 @ W2; alpha coeffs
__global__ void k_gemm2(const float* __restrict__ out1, const void* __restrict__ b1,
                        const void* __restrict__ w2, const void* __restrict__ a_s2,
                        const void* __restrict__ a_d2, float* __restrict__ h2,
                        float* __restrict__ as2, float* __restrict__ ad2,
                        const int* __restrict__ flag) {
  const int isbf = *flag;
  __shared__ float w2s[D1 * CLS];
  __shared__ float b1s[D1];
  int tid = threadIdx.x;
  for (int idx = tid; idx < D1 * CLS; idx += 256) w2s[idx] = ldin(w2, isbf, idx);
  for (int idx = tid; idx < D1; idx += 256) b1s[idx] = ldin(b1, isbf, idx);
  __syncthreads();
  int wave = tid >> 6, lane = tid & 63;
  int n = blockIdx.x * 4 + wave;
  if (n >= N_NODES) return;
  float acc[CLS] = {0.f, 0.f, 0.f, 0.f, 0.f, 0.f};
#pragma unroll
  for (int t = 0; t < D1 / 64; ++t) {
    int k = t * 64 + lane;
    float xv = out1[(size_t)n * D1 + k] + b1s[k];
    xv = xv > 0.f ? xv : (__expf(xv) - 1.f);  // ELU
#pragma unroll
    for (int c = 0; c < CLS; ++c) acc[c] += xv * w2s[k * CLS + c];
  }
#pragma unroll
  for (int off = 32; off > 0; off >>= 1)
#pragma unroll
    for (int c = 0; c < CLS; ++c) acc[c] += __shfl_down(acc[c], off, 64);
  if (lane == 0) {
    float s0 = 0.f, s1 = 0.f;
#pragma unroll
    for (int c = 0; c < CLS; ++c) {
      h2[n * CLS + c] = acc[c];
      s0 += acc[c] * ldin(a_s2, isbf, c);
      s1 += acc[c] * ldin(a_d2, isbf, c);
    }
    as2[n] = s0; ad2[n] = s1;
  }
}

// ---------------------------------------------------------------- edge pass layer 2
__global__ void k_edge2(const int* __restrict__ ei, const float* __restrict__ as2,
                        const float* __restrict__ ad2, float* __restrict__ p2,
                        float* __restrict__ denom2) {
  int i = blockIdx.x * blockDim.x + threadIdx.x;
  if (i >= EN_TOT) return;
  int s, d;
  if (i < N_EDGES) { s = ei[i]; d = ei[N_EDGES + i]; }
  else { s = d = i - N_EDGES; }
  float e = as2[s] + ad2[d];
  e = e > 0.f ? e : NEG_SLOPE * e;
  float p = __expf(e);
  p2[i] = p;
  atomicAdd(&denom2[d], p);
}

__global__ void k_norm2(const int* __restrict__ ei, float* __restrict__ p2,
                        const float* __restrict__ denom2) {
  int i = blockIdx.x * blockDim.x + threadIdx.x;
  if (i >= EN_TOT) return;
  int d = (i < N_EDGES) ? ei[N_EDGES + i] : i - N_EDGES;
  p2[i] = p2[i] / denom2[d];
}

__global__ void k_agg2(const int* __restrict__ ei, const float* __restrict__ p2,
                       const float* __restrict__ h2, float* __restrict__ out2) {
  int gid = blockIdx.x * blockDim.x + threadIdx.x;
  if (gid >= EN_TOT * CLS) return;
  int i = gid / CLS;
  int c = gid - i * CLS;
  int s, d;
  if (i < N_EDGES) { s = ei[i]; d = ei[N_EDGES + i]; }
  else { s = d = i - N_EDGES; }
  atomicAdd(&out2[d * CLS + c], p2[i] * h2[s * CLS + c]);
}

// ---------------------------------------------------------------- final: + b2, store in detected output dtype
__global__ void k_final(const float* __restrict__ out2, const void* __restrict__ b2,
                        void* __restrict__ out, const int* __restrict__ flag) {
  const int isbf = *flag;
  int gid = blockIdx.x * blockDim.x + threadIdx.x;
  if (gid >= N_NODES * CLS) return;
  int c = gid % CLS;
  float v = out2[gid] + ldin(b2, isbf, c);
  if (isbf) ((unsigned short*)out)[gid] = f2bf(v);
  else      ((float*)out)[gid] = v;
}

// ================================================================ launch
extern "C" void kernel_launch(void* const* d_in, const int* in_sizes, int n_in,
                              void* d_out, int out_size, void* d_ws, size_t ws_size,
                              hipStream_t stream) {
  const void* x    = d_in[0];
  const int*  ei   = (const int*)d_in[1];
  const void* W1   = d_in[2];
  const void* a_s1 = d_in[3];
  const void* a_d1 = d_in[4];
  const void* b1   = d_in[5];
  const void* W2   = d_in[6];
  const void* a_s2 = d_in[7];
  const void* a_d2 = d_in[8];
  const void* b2   = d_in[9];

  char* ws = (char*)d_ws;
  size_t off = 0;
  auto alloc = [&](size_t b) { size_t r = off; off += (b + 255) & ~(size_t)255; return r; };
  int*   flag   = (int*)  (ws + alloc(256));
  unsigned short* w1t = (unsigned short*)(ws + alloc((size_t)D1 * F_IN * 2));
  unsigned short* h1  = (unsigned short*)(ws + alloc((size_t)N_NODES * D1 * 2));
  float* p1     = (float*)(ws + alloc((size_t)EN_TOT * HEADS * 4));
  float* as1    = (float*)(ws + alloc((size_t)N_NODES * HEADS * 4));
  float* ad1    = (float*)(ws + alloc((size_t)N_NODES * HEADS * 4));
  float* as2v   = (float*)(ws + alloc((size_t)N_NODES * 4));
  float* ad2v   = (float*)(ws + alloc((size_t)N_NODES * 4));
  float* p2     = (float*)(ws + alloc((size_t)EN_TOT * 4));
  float* h2     = (float*)(ws + alloc((size_t)N_NODES * CLS * 4));
  size_t zstart = off;
  float* out1   = (float*)(ws + alloc((size_t)N_NODES * D1 * 4));
  float* denom1 = (float*)(ws + alloc((size_t)N_NODES * HEADS * 4));
  float* denom2 = (float*)(ws + alloc((size_t)N_NODES * 4));
  float* out2   = (float*)(ws + alloc((size_t)N_NODES * CLS * 4));
  size_t zbytes = off - zstart;

  k_detect<<<1, 256, 0, stream>>>(x, flag);
  k_zero<<<(int)((zbytes / 4 + 255) / 256), 256, 0, stream>>>((float*)(ws + zstart),
                                                              (long long)(zbytes / 4));
  k_transpose<<<dim3(D1 / 32, F_IN / 32), dim3(32, 8), 0, stream>>>(W1, w1t, flag);
  k_gemm1<<<dim3(4, (N_NODES + 127) / 128), 256, 0, stream>>>(x, w1t, h1, flag);
  k_alpha1<<<N_NODES, 256, 0, stream>>>(h1, a_s1, a_d1, as1, ad1, flag);
  int eb = (EN_TOT + 255) / 256;
  k_edge1<<<eb, 256, 0, stream>>>(ei, as1, ad1, p1, denom1);
  k_norm1<<<eb, 256, 0, stream>>>(ei, p1, denom1);
  k_agg1<<<16384, 256, 0, stream>>>(ei, p1, h1, out1);
  k_gemm2<<<N_NODES / 4, 256, 0, stream>>>(out1, b1, W2, a_s2, a_d2, h2, as2v, ad2v, flag);
  k_edge2<<<eb, 256, 0, stream>>>(ei, as2v, ad2v, p2, denom2);
  k_norm2<<<eb, 256, 0, stream>>>(ei, p2, denom2);
  k_agg2<<<(EN_TOT * CLS + 255) / 256, 256, 0, stream>>>(ei, p2, h2, out2);
  k_final<<<(N_NODES * CLS + 255) / 256, 256, 0, stream>>>(out2, b2, d_out, flag);
}

// Round 3
// 1158.895 us; speedup vs baseline: 3.9146x; 3.9146x over previous
//
#include <hip/hip_runtime.h>
#include <hip/hip_bf16.h>
#include <stdint.h>
#include <stddef.h>

#define N_NODES 30000
#define N_EDGES 480000
#define EN_TOT  (N_EDGES + N_NODES)   /* 510000 with self loops */
#define F_IN 4096
#define HEADS 4
#define HID 128
#define D1 (HEADS * HID)              /* 512 */
#define CLS 6
#define NEG_SLOPE 0.2f

typedef __attribute__((ext_vector_type(4))) unsigned int u32x4;
typedef __attribute__((ext_vector_type(8))) short short8;
typedef __attribute__((ext_vector_type(4))) float f32x4;

__device__ __forceinline__ float bf2f(unsigned short u) {
  return __uint_as_float(((unsigned int)u) << 16);
}
__device__ __forceinline__ unsigned short f2bf(float f) {
  unsigned int u = __float_as_uint(f);
  unsigned int r = (u + 0x7FFFu + ((u >> 16) & 1u)) >> 16;  // RNE
  return (unsigned short)r;
}
__device__ __forceinline__ float ldin(const void* p, int isbf, size_t i) {
  if (isbf) return bf2f(((const unsigned short*)p)[i]);
  return ((const float*)p)[i];
}

// ---------------------------------------------------------------- dtype detect
__global__ void k_detect(const void* xraw, int* flag) {
  __shared__ int bad;
  if (threadIdx.x == 0) bad = 0;
  __syncthreads();
  const unsigned short* u = (const unsigned short*)xraw;
  int cnt = 0;
  for (int i = threadIdx.x; i < 8192; i += 256) {
    float v = bf2f(u[i]);
    if (!isfinite(v) || fabsf(v) > 1e8f) cnt++;
  }
  atomicAdd(&bad, cnt);
  __syncthreads();
  if (threadIdx.x == 0) *flag = (bad > 8) ? 0 : 1;  // 1 = bf16 mode
}

// ---------------------------------------------------------------- zero fill (deg only)
__global__ void k_zero(int* __restrict__ p, int n) {
  int i = blockIdx.x * blockDim.x + threadIdx.x;
  if (i < n) p[i] = 0;
}

// ---------------------------------------------------------------- CSR build
__global__ void k_hist(const int* __restrict__ ei, int* __restrict__ deg) {
  int i = blockIdx.x * blockDim.x + threadIdx.x;
  if (i >= EN_TOT) return;
  int d = (i < N_EDGES) ? ei[N_EDGES + i] : i - N_EDGES;
  atomicAdd(&deg[d], 1);
}

// single-block exclusive scan over 30000 degrees -> offs[30001], cursor copy
__global__ void k_scan(const int* __restrict__ deg, int* __restrict__ offs,
                       int* __restrict__ cursor) {
  __shared__ int sums[1024];
  const int tid = threadIdx.x;
  const int CH = (N_NODES + 1023) / 1024;  // 30
  int base = tid * CH;
  int local = 0;
  for (int j = 0; j < CH; j++) {
    int idx = base + j;
    if (idx < N_NODES) local += deg[idx];
  }
  sums[tid] = local;
  __syncthreads();
  for (int off = 1; off < 1024; off <<= 1) {
    int v = (tid >= off) ? sums[tid - off] : 0;
    __syncthreads();
    sums[tid] += v;
    __syncthreads();
  }
  int run = (tid == 0) ? 0 : sums[tid - 1];
  for (int j = 0; j < CH; j++) {
    int idx = base + j;
    if (idx < N_NODES) {
      offs[idx] = run;
      cursor[idx] = run;
      run += deg[idx];
    }
  }
  if (tid == 1023) offs[N_NODES] = sums[1023];
}

__global__ void k_scatter(const int* __restrict__ ei, int* __restrict__ cursor,
                          int* __restrict__ csr_src, int* __restrict__ csr_eid) {
  int i = blockIdx.x * blockDim.x + threadIdx.x;
  if (i >= EN_TOT) return;
  int s, d;
  if (i < N_EDGES) { s = ei[i]; d = ei[N_EDGES + i]; }
  else { s = d = i - N_EDGES; }
  int pos = atomicAdd(&cursor[d], 1);
  csr_src[pos] = s;
  csr_eid[pos] = i;
}

// ---------------------------------------------------------------- W1 transpose: [F_IN, D1] -> bf16 [D1, F_IN]
__global__ void k_transpose(const void* __restrict__ in, unsigned short* __restrict__ out,
                            const int* __restrict__ flag) {
  const int isbf = *flag;
  __shared__ unsigned short t[32][33];
  int bx = blockIdx.x * 32;
  int by = blockIdx.y * 32;
  int x = threadIdx.x, y = threadIdx.y;  // 32 x 8
#pragma unroll
  for (int i = 0; i < 32; i += 8)
    t[y + i][x] = f2bf(ldin(in, isbf, (size_t)(by + y + i) * D1 + bx + x));
  __syncthreads();
#pragma unroll
  for (int i = 0; i < 32; i += 8)
    out[(size_t)(bx + y + i) * F_IN + by + x] = t[x][y + i];
}

// ---------------------------------------------------------------- GEMM1: h1[30000,512] = x @ W1 (bf16 MFMA)
__launch_bounds__(256, 2)
__global__ void k_gemm1(const void* __restrict__ xraw, const unsigned short* __restrict__ w1t,
                        unsigned short* __restrict__ h1, const int* __restrict__ flag) {
  const int isbf = *flag;
  __shared__ __align__(16) unsigned short As[128 * 32];
  __shared__ __align__(16) unsigned short Bs[128 * 32];
  const int tid = threadIdx.x;
  const int wave = tid >> 6, lane = tid & 63;
  const int l15 = lane & 15, lq = lane >> 4;
  const int wm = (wave & 1) * 64, wn = (wave >> 1) * 64;
  const int n0 = blockIdx.x * 128;
  const int m0 = blockIdx.y * 128;

  f32x4 acc[4][4];
#pragma unroll
  for (int i = 0; i < 4; i++)
#pragma unroll
    for (int j = 0; j < 4; j++) acc[i][j] = (f32x4){0.f, 0.f, 0.f, 0.f};

  const u32x4* As4 = (const u32x4*)As;
  const u32x4* Bs4 = (const u32x4*)Bs;

  for (int k0 = 0; k0 < F_IN; k0 += 32) {
#pragma unroll
    for (int it = 0; it < 2; ++it) {
      int idx = it * 256 + tid;
      int row = idx >> 2;
      int c8  = (idx & 3) * 8;
      int gr  = m0 + row;
      u32x4 av = {0u, 0u, 0u, 0u};
      if (gr < N_NODES) {
        size_t eoff = (size_t)gr * F_IN + k0 + c8;
        if (isbf) {
          av = *(const u32x4*)((const unsigned short*)xraw + eoff);
        } else {
          const float* xf = (const float*)xraw + eoff;
          float4 v0 = *(const float4*)xf;
          float4 v1 = *(const float4*)(xf + 4);
          av[0] = (unsigned int)f2bf(v0.x) | ((unsigned int)f2bf(v0.y) << 16);
          av[1] = (unsigned int)f2bf(v0.z) | ((unsigned int)f2bf(v0.w) << 16);
          av[2] = (unsigned int)f2bf(v1.x) | ((unsigned int)f2bf(v1.y) << 16);
          av[3] = (unsigned int)f2bf(v1.z) | ((unsigned int)f2bf(v1.w) << 16);
        }
      }
      u32x4 bv = *(const u32x4*)(w1t + (size_t)(n0 + row) * F_IN + k0 + c8);
      ((u32x4*)As)[idx] = av;
      ((u32x4*)Bs)[idx] = bv;
    }
    __syncthreads();
    short8 af[4], bfr[4];
#pragma unroll
    for (int i = 0; i < 4; i++)
      af[i] = __builtin_bit_cast(short8, As4[(wm + 16 * i + l15) * 4 + lq]);
#pragma unroll
    for (int j = 0; j < 4; j++)
      bfr[j] = __builtin_bit_cast(short8, Bs4[(wn + 16 * j + l15) * 4 + lq]);
#pragma unroll
    for (int i = 0; i < 4; i++)
#pragma unroll
      for (int j = 0; j < 4; j++)
        acc[i][j] = __builtin_amdgcn_mfma_f32_16x16x32_bf16(af[i], bfr[j], acc[i][j], 0, 0, 0);
    __syncthreads();
  }
#pragma unroll
  for (int i = 0; i < 4; i++) {
#pragma unroll
    for (int r = 0; r < 4; r++) {
      int row = m0 + wm + 16 * i + lq * 4 + r;
      if (row < N_NODES) {
#pragma unroll
        for (int j = 0; j < 4; j++) {
          int col = n0 + wn + 16 * j + l15;
          h1[(size_t)row * D1 + col] = f2bf(acc[i][j][r]);
        }
      }
    }
  }
}

// ---------------------------------------------------------------- per-node attention coefficients, layer 1
__global__ void k_alpha1(const unsigned short* __restrict__ h1, const void* __restrict__ a_s,
                         const void* __restrict__ a_d, float* __restrict__ as1,
                         float* __restrict__ ad1, const int* __restrict__ flag) {
  const int isbf = *flag;
  int n = blockIdx.x;
  int h = threadIdx.x >> 6;
  int lane = threadIdx.x & 63;
  const unsigned short* hp = h1 + (size_t)n * D1 + h * HID;
  float s0 = 0.f, s1 = 0.f;
#pragma unroll
  for (int t = 0; t < 2; ++t) {
    int c = lane + t * 64;
    float hv = bf2f(hp[c]);
    s0 += hv * ldin(a_s, isbf, h * HID + c);
    s1 += hv * ldin(a_d, isbf, h * HID + c);
  }
#pragma unroll
  for (int off = 32; off > 0; off >>= 1) {
    s0 += __shfl_down(s0, off, 64);
    s1 += __shfl_down(s1, off, 64);
  }
  if (lane == 0) { as1[n * HEADS + h] = s0; ad1[n * HEADS + h] = s1; }
}

// ---------------------------------------------------------------- edge logits layer 1 (unnormalized p; denom folded into agg)
__global__ void k_edge1(const int* __restrict__ ei, const float* __restrict__ as1,
                        const float* __restrict__ ad1, float* __restrict__ p1) {
  int i = blockIdx.x * blockDim.x + threadIdx.x;
  if (i >= EN_TOT) return;
  int s, d;
  if (i < N_EDGES) { s = ei[i]; d = ei[N_EDGES + i]; }
  else { s = d = i - N_EDGES; }
#pragma unroll
  for (int h = 0; h < HEADS; ++h) {
    float e = as1[s * HEADS + h] + ad1[d * HEADS + h];
    e = e > 0.f ? e : NEG_SLOPE * e;
    p1[i * HEADS + h] = __expf(e);
  }
}

// ---------------------------------------------------------------- aggregation layer 1, CSR gather (no atomics)
// block = 256 threads = one dst node; thread t covers channels 2t, 2t+1 (same head)
#define CHUNK 256
__launch_bounds__(256, 4)
__global__ void k_agg1_csr(const int* __restrict__ offs, const int* __restrict__ csr_src,
                           const int* __restrict__ csr_eid, const float* __restrict__ p1,
                           const unsigned short* __restrict__ h1, float* __restrict__ out1) {
  __shared__ int s_src[CHUNK];
  __shared__ float4 s_p[CHUNK];
  const int n = blockIdx.x;
  const int tid = threadIdx.x;
  const int c = tid * 2;
  const int h = c >> 7;
  const int start = offs[n], end = offs[n + 1];
  float a0 = 0.f, a1 = 0.f, dsum = 0.f;
  for (int base = start; base < end; base += CHUNK) {
    int cnt = end - base;
    if (cnt > CHUNK) cnt = CHUNK;
    for (int idx = tid; idx < cnt; idx += 256) {
      int e = base + idx;
      s_src[idx] = csr_src[e];
      int eid = csr_eid[e];
      s_p[idx] = *(const float4*)(p1 + (size_t)eid * HEADS);
    }
    __syncthreads();
    for (int j = 0; j < cnt; ++j) {
      int s = s_src[j];
      float p = ((const float*)&s_p[j])[h];   // wave-uniform h -> LDS broadcast
      const unsigned short* hp = h1 + (size_t)s * D1 + c;
      unsigned int hv = *(const unsigned int*)hp;  // 2 bf16
      a0 += p * bf2f((unsigned short)(hv & 0xFFFFu));
      a1 += p * bf2f((unsigned short)(hv >> 16));
      dsum += p;
    }
    __syncthreads();
  }
  float inv = 1.f / dsum;   // self-loop guarantees dsum > 0
  float2 o = {a0 * inv, a1 * inv};
  *(float2*)(out1 + (size_t)n * D1 + c) = o;
}

// ---------------------------------------------------------------- layer 2 fused: x2 = elu(out1 + b1); h2 = x2 @ W2; alpha coeffs
__global__ void k_gemm2(const float* __restrict__ out1, const void* __restrict__ b1,
                        const void* __restrict__ w2, const void* __restrict__ a_s2,
                        const void* __restrict__ a_d2, float* __restrict__ h2,
                        float* __restrict__ as2, float* __restrict__ ad2,
                        const int* __restrict__ flag) {
  const int isbf = *flag;
  __shared__ float w2s[D1 * CLS];
  __shared__ float b1s[D1];
  int tid = threadIdx.x;
  for (int idx = tid; idx < D1 * CLS; idx += 256) w2s[idx] = ldin(w2, isbf, idx);
  for (int idx = tid; idx < D1; idx += 256) b1s[idx] = ldin(b1, isbf, idx);
  __syncthreads();
  int wave = tid >> 6, lane = tid & 63;
  int n = blockIdx.x * 4 + wave;
  if (n >= N_NODES) return;
  float acc[CLS] = {0.f, 0.f, 0.f, 0.f, 0.f, 0.f};
#pragma unroll
  for (int t = 0; t < D1 / 64; ++t) {
    int k = t * 64 + lane;
    float xv = out1[(size_t)n * D1 + k] + b1s[k];
    xv = xv > 0.f ? xv : (__expf(xv) - 1.f);  // ELU
#pragma unroll
    for (int c = 0; c < CLS; ++c) acc[c] += xv * w2s[k * CLS + c];
  }
#pragma unroll
  for (int off = 32; off > 0; off >>= 1)
#pragma unroll
    for (int c = 0; c < CLS; ++c) acc[c] += __shfl_down(acc[c], off, 64);
  if (lane == 0) {
    float s0 = 0.f, s1 = 0.f;
#pragma unroll
    for (int c = 0; c < CLS; ++c) {
      h2[n * CLS + c] = acc[c];
      s0 += acc[c] * ldin(a_s2, isbf, c);
      s1 += acc[c] * ldin(a_d2, isbf, c);
    }
    as2[n] = s0; ad2[n] = s1;
  }
}

// ---------------------------------------------------------------- edge logits layer 2 (unnormalized)
__global__ void k_edge2(const int* __restrict__ ei, const float* __restrict__ as2,
                        const float* __restrict__ ad2, float* __restrict__ p2) {
  int i = blockIdx.x * blockDim.x + threadIdx.x;
  if (i >= EN_TOT) return;
  int s, d;
  if (i < N_EDGES) { s = ei[i]; d = ei[N_EDGES + i]; }
  else { s = d = i - N_EDGES; }
  float e = as2[s] + ad2[d];
  e = e > 0.f ? e : NEG_SLOPE * e;
  p2[i] = __expf(e);
}

// ---------------------------------------------------------------- aggregation layer 2, CSR + fused bias + output store
// wave per node; lanes stride over edges
__global__ void k_agg2_csr(const int* __restrict__ offs, const int* __restrict__ csr_src,
                           const int* __restrict__ csr_eid, const float* __restrict__ p2,
                           const float* __restrict__ h2, const void* __restrict__ b2,
                           void* __restrict__ out, const int* __restrict__ flag) {
  const int isbf = *flag;
  int wave = threadIdx.x >> 6, lane = threadIdx.x & 63;
  int n = blockIdx.x * 4 + wave;
  if (n >= N_NODES) return;
  int start = offs[n], end = offs[n + 1];
  float acc[CLS] = {0.f, 0.f, 0.f, 0.f, 0.f, 0.f};
  float dsum = 0.f;
  for (int e = start + lane; e < end; e += 64) {
    int s = csr_src[e];
    int eid = csr_eid[e];
    float p = p2[eid];
    dsum += p;
    const float* hp = h2 + (size_t)s * CLS;
#pragma unroll
    for (int c = 0; c < CLS; ++c) acc[c] += p * hp[c];
  }
#pragma unroll
  for (int off = 32; off > 0; off >>= 1) {
    dsum += __shfl_down(dsum, off, 64);
#pragma unroll
    for (int c = 0; c < CLS; ++c) acc[c] += __shfl_down(acc[c], off, 64);
  }
  if (lane == 0) {
    float inv = 1.f / dsum;
#pragma unroll
    for (int c = 0; c < CLS; ++c) {
      float v = acc[c] * inv + ldin(b2, isbf, c);
      if (isbf) ((unsigned short*)out)[n * CLS + c] = f2bf(v);
      else      ((float*)out)[n * CLS + c] = v;
    }
  }
}

// ================================================================ launch
extern "C" void kernel_launch(void* const* d_in, const int* in_sizes, int n_in,
                              void* d_out, int out_size, void* d_ws, size_t ws_size,
                              hipStream_t stream) {
  const void* x    = d_in[0];
  const int*  ei   = (const int*)d_in[1];
  const void* W1   = d_in[2];
  const void* a_s1 = d_in[3];
  const void* a_d1 = d_in[4];
  const void* b1   = d_in[5];
  const void* W2   = d_in[6];
  const void* a_s2 = d_in[7];
  const void* a_d2 = d_in[8];
  const void* b2   = d_in[9];

  char* ws = (char*)d_ws;
  size_t off = 0;
  auto alloc = [&](size_t b) { size_t r = off; off += (b + 255) & ~(size_t)255; return r; };
  int*   flag    = (int*)(ws + alloc(256));
  unsigned short* w1t = (unsigned short*)(ws + alloc((size_t)D1 * F_IN * 2));
  unsigned short* h1  = (unsigned short*)(ws + alloc((size_t)N_NODES * D1 * 2));
  float* p1      = (float*)(ws + alloc((size_t)EN_TOT * HEADS * 4));
  float* as1     = (float*)(ws + alloc((size_t)N_NODES * HEADS * 4));
  float* ad1     = (float*)(ws + alloc((size_t)N_NODES * HEADS * 4));
  float* as2v    = (float*)(ws + alloc((size_t)N_NODES * 4));
  float* ad2v    = (float*)(ws + alloc((size_t)N_NODES * 4));
  float* p2      = (float*)(ws + alloc((size_t)EN_TOT * 4));
  float* h2      = (float*)(ws + alloc((size_t)N_NODES * CLS * 4));
  float* out1    = (float*)(ws + alloc((size_t)N_NODES * D1 * 4));
  int*   deg     = (int*)(ws + alloc((size_t)N_NODES * 4));
  int*   offs    = (int*)(ws + alloc((size_t)(N_NODES + 1) * 4));
  int*   cursor  = (int*)(ws + alloc((size_t)N_NODES * 4));
  int*   csr_src = (int*)(ws + alloc((size_t)EN_TOT * 4));
  int*   csr_eid = (int*)(ws + alloc((size_t)EN_TOT * 4));

  int eb = (EN_TOT + 255) / 256;
  k_detect<<<1, 256, 0, stream>>>(x, flag);
  k_zero<<<(N_NODES + 255) / 256, 256, 0, stream>>>(deg, N_NODES);
  k_hist<<<eb, 256, 0, stream>>>(ei, deg);
  k_scan<<<1, 1024, 0, stream>>>(deg, offs, cursor);
  k_scatter<<<eb, 256, 0, stream>>>(ei, cursor, csr_src, csr_eid);
  k_transpose<<<dim3(D1 / 32, F_IN / 32), dim3(32, 8), 0, stream>>>(W1, w1t, flag);
  k_gemm1<<<dim3(4, (N_NODES + 127) / 128), 256, 0, stream>>>(x, w1t, h1, flag);
  k_alpha1<<<N_NODES, 256, 0, stream>>>(h1, a_s1, a_d1, as1, ad1, flag);
  k_edge1<<<eb, 256, 0, stream>>>(ei, as1, ad1, p1);
  k_agg1_csr<<<N_NODES, 256, 0, stream>>>(offs, csr_src, csr_eid, p1, h1, out1);
  k_gemm2<<<(N_NODES + 3) / 4, 256, 0, stream>>>(out1, b1, W2, a_s2, a_d2, h2, as2v, ad2v, flag);
  k_edge2<<<eb, 256, 0, stream>>>(ei, as2v, ad2v, p2);
  k_agg2_csr<<<(N_NODES + 3) / 4, 256, 0, stream>>>(offs, csr_src, csr_eid, p2, h2, b2,
                                                    d_out, flag);
}